// Round 2
// baseline (1548.741 us; speedup 1.0000x reference)
//
#include <hip/hip_runtime.h>

#define NN 100000
#define NE 1600000
#define DD 128

typedef __attribute__((ext_vector_type(8))) short bf16x8;
typedef __attribute__((ext_vector_type(4))) float f32x4;

__device__ __forceinline__ ushort f2bf(float f) {
    union { float f; uint i; } v; v.f = f;
    uint i = v.i;
    return (ushort)((i + 0x7fffu + ((i >> 16) & 1u)) >> 16);
}

// agg = x (fp32 copy); zero the stats region
__global__ void k_init(const float* __restrict__ x, float* __restrict__ agg,
                       float* __restrict__ stats) {
    int gid = blockIdx.x * 256 + threadIdx.x;
    if (gid < 512) stats[gid] = 0.f;
    ((float4*)agg)[gid] = ((const float4*)x)[gid];
}

// one wave per edge, 2 features per lane
__global__ void k_scatter(const float* __restrict__ x, const int* __restrict__ ei,
                          float* __restrict__ agg) {
    int t = blockIdx.x * 256 + threadIdx.x;
    int e = t >> 6, lane = t & 63;   // e is wave-uniform
    int s = ei[e];
    int d = ei[NE + e];
    float2 v = ((const float2*)(x + (size_t)s * DD))[lane];
    float* ar = agg + (size_t)d * DD + lane * 2;
    atomicAdd(ar,     v.x);
    atomicAdd(ar + 1, v.y);
}

// MODE 1: A = agg, no pre-transform, bias, emit colstats
// MODE 2: A = t1,  pre-transform relu(a*t+c), bias, emit colstats
// MODE 3: A = t2,  pre-transform relu(a*t+c), no bias, relu output, no stats
template <int MODE>
__global__ __launch_bounds__(256) void k_gemm(const float* __restrict__ Ain,
                                              const float* __restrict__ W,
                                              const float* __restrict__ bias,
                                              const float* __restrict__ ac,
                                              float* __restrict__ Out,
                                              float* __restrict__ stats) {
    __shared__ ushort lw[DD * 136];     // W[c][k] as bf16, row padded 128->136
    __shared__ float red[2][4][DD];

    int tid = threadIdx.x;
    // stage W (128x128 fp32 -> bf16) into LDS, 8 elems per thread per iter
#pragma unroll
    for (int it = 0; it < 8; ++it) {
        int idx = (it * 256 + tid) * 8;
        int r = idx >> 7, k = idx & 127;
        float4 u0 = *(const float4*)(W + idx);
        float4 u1 = *(const float4*)(W + idx + 4);
        uint4 pk;
        pk.x = (uint)f2bf(u0.x) | ((uint)f2bf(u0.y) << 16);
        pk.y = (uint)f2bf(u0.z) | ((uint)f2bf(u0.w) << 16);
        pk.z = (uint)f2bf(u1.x) | ((uint)f2bf(u1.y) << 16);
        pk.w = (uint)f2bf(u1.z) | ((uint)f2bf(u1.w) << 16);
        *(uint4*)&lw[r * 136 + k] = pk;
    }
    __syncthreads();

    int wave = tid >> 6, lane = tid & 63;
    int lm = lane & 15, quad = lane >> 4;
    int row0 = blockIdx.x * 64 + wave * 16;
    int arow = row0 + lm;
    bool rowok = arow < NN;
    int ar = rowok ? arow : 0;

    // A fragments: A[m=lane&15][k = kb*32 + quad*8 + j]
    bf16x8 afrag[4];
#pragma unroll
    for (int kb = 0; kb < 4; ++kb) {
        int k0 = kb * 32 + quad * 8;
        const float* ap = Ain + (size_t)ar * DD + k0;
        float4 u0 = ((const float4*)ap)[0];
        float4 u1 = ((const float4*)ap)[1];
        float vs[8] = {u0.x, u0.y, u0.z, u0.w, u1.x, u1.y, u1.z, u1.w};
        bf16x8 af;
#pragma unroll
        for (int j = 0; j < 8; ++j) {
            float v = vs[j];
            if constexpr (MODE != 1) {
                int k = k0 + j;
                v = fmaxf(fmaf(v, ac[k], ac[DD + k]), 0.f);
            }
            af[j] = (short)f2bf(rowok ? v : 0.f);
        }
        afrag[kb] = af;
    }

    // accumulators; bias in C init (bias depends only on col)
    f32x4 acc[8];
#pragma unroll
    for (int nt = 0; nt < 8; ++nt) {
        float bv = (MODE == 3) ? 0.f : bias[nt * 16 + lm];
        acc[nt] = (f32x4){bv, bv, bv, bv};
    }

#pragma unroll
    for (int kb = 0; kb < 4; ++kb) {
#pragma unroll
        for (int nt = 0; nt < 8; ++nt) {
            bf16x8 bfrag = *(const bf16x8*)&lw[(nt * 16 + lm) * 136 + kb * 32 + quad * 8];
            acc[nt] = __builtin_amdgcn_mfma_f32_16x16x32_bf16(afrag[kb], bfrag, acc[nt], 0, 0, 0);
        }
    }

    // epilogue: store + column sum / sumsq; C/D: col=lane&15, row=quad*4+r
    float csum[8], csq[8];
#pragma unroll
    for (int nt = 0; nt < 8; ++nt) {
        int col = nt * 16 + lm;
        float s = 0.f, q = 0.f;
#pragma unroll
        for (int r = 0; r < 4; ++r) {
            int row = row0 + quad * 4 + r;
            float v = acc[nt][r];
            if (MODE == 3) v = fmaxf(v, 0.f);
            if (row < NN) {
                Out[(size_t)row * DD + col] = v;
                s += v;
                q += v * v;
            }
        }
        csum[nt] = s; csq[nt] = q;
    }

    if constexpr (MODE != 3) {
#pragma unroll
        for (int nt = 0; nt < 8; ++nt) {
            float s = csum[nt], q = csq[nt];
            s += __shfl_down(s, 16, 64); q += __shfl_down(q, 16, 64);
            s += __shfl_down(s, 32, 64); q += __shfl_down(q, 32, 64);
            if (quad == 0) {
                red[0][wave][nt * 16 + lm] = s;
                red[1][wave][nt * 16 + lm] = q;
            }
        }
        __syncthreads();
        if (tid < DD) {
            float S = red[0][0][tid] + red[0][1][tid] + red[0][2][tid] + red[0][3][tid];
            float Q = red[1][0][tid] + red[1][1][tid] + red[1][2][tid] + red[1][3][tid];
            atomicAdd(&stats[tid], S);
            atomicAdd(&stats[DD + tid], Q);
        }
    }
}

// mean/var -> scale a, shift c for fused BN apply
__global__ void k_finalize(const float* __restrict__ stats, const float* __restrict__ g,
                           const float* __restrict__ be, float* __restrict__ ac) {
    int c = threadIdx.x;
    float inv = 1.f / (float)NN;
    float mean = stats[c] * inv;
    float var = stats[DD + c] * inv - mean * mean;
    float a = g[c] * rsqrtf(var + 1e-5f);
    ac[c] = a;
    ac[DD + c] = be[c] - mean * a;
}

extern "C" void kernel_launch(void* const* d_in, const int* in_sizes, int n_in,
                              void* d_out, int out_size, void* d_ws, size_t ws_size,
                              hipStream_t stream) {
    const float* x   = (const float*)d_in[0];
    const int* ei    = (const int*)d_in[1];
    const float* W1  = (const float*)d_in[2];
    const float* b1  = (const float*)d_in[3];
    const float* g1  = (const float*)d_in[4];
    const float* be1 = (const float*)d_in[5];
    const float* W2  = (const float*)d_in[6];
    const float* b2  = (const float*)d_in[7];
    const float* g2  = (const float*)d_in[8];
    const float* be2 = (const float*)d_in[9];
    const float* W3  = (const float*)d_in[10];

    // ws layout: agg f32 [NN*DD] | stats f32 [512] | ac f32 [512]
    // t1 lives in d_out (fp32); t2 reuses the agg buffer (dead after gemm1)
    float* agg   = (float*)d_ws;
    float* stats = agg + (size_t)NN * DD;
    float* ac    = stats + 512;
    float* t1    = (float*)d_out;
    float* t2    = agg;
    float* outp  = (float*)d_out;

    int gblk = (NN + 63) / 64;
    k_init<<<NN * DD / 1024, 256, 0, stream>>>(x, agg, stats);
    k_scatter<<<NE / 4, 256, 0, stream>>>(x, ei, agg);
    k_gemm<1><<<gblk, 256, 0, stream>>>(agg, W1, b1, nullptr, t1, stats);
    k_finalize<<<1, DD, 0, stream>>>(stats, g1, be1, ac);
    k_gemm<2><<<gblk, 256, 0, stream>>>(t1, W2, b2, ac, t2, stats + 256);
    k_finalize<<<1, DD, 0, stream>>>(stats + 256, g2, be2, ac + 256);
    k_gemm<3><<<gblk, 256, 0, stream>>>(t2, W3, nullptr, ac + 256, outp, nullptr);
}

// Round 3
// 536.441 us; speedup vs baseline: 2.8871x; 2.8871x over previous
//
#include <hip/hip_runtime.h>

#define NN 100000
#define NE 1600000
#define DD 128
#define NN2 100096   // 391*256, padded node count for scan
#define GBLK 391

typedef __attribute__((ext_vector_type(8))) short bf16x8;
typedef __attribute__((ext_vector_type(4))) float f32x4;

union u4bf8 { uint4 u; bf16x8 v; };

__device__ __forceinline__ ushort f2bf(float f) {
    union { float f; uint i; } v; v.f = f;
    uint i = v.i;
    return (ushort)((i + 0x7fffu + ((i >> 16) & 1u)) >> 16);
}
__device__ __forceinline__ float bf2f(ushort u) {
    union { uint i; float f; } v; v.i = ((uint)u) << 16; return v.f;
}

// zero deg[NN2] and stats[512]
__global__ void k_zero(int* __restrict__ deg, float* __restrict__ stats) {
    int i = blockIdx.x * 256 + threadIdx.x;
    if (i < NN2) deg[i] = 0;
    else stats[i - NN2] = 0.f;
}

__global__ void k_hist(const int* __restrict__ ei, int* __restrict__ deg) {
    int e = blockIdx.x * 256 + threadIdx.x;
    atomicAdd(&deg[ei[NE + e]], 1);
}

// per-block exclusive scan (256 elems) + block sums
__global__ void k_scanA(const int* __restrict__ deg, int* __restrict__ loc,
                        int* __restrict__ bsum) {
    __shared__ int sd[256];
    int t = threadIdx.x;
    int i = blockIdx.x * 256 + t;
    int v = deg[i];
    sd[t] = v; __syncthreads();
#pragma unroll
    for (int o = 1; o < 256; o <<= 1) {
        int u = (t >= o) ? sd[t - o] : 0;
        __syncthreads();
        sd[t] += u;
        __syncthreads();
    }
    loc[i] = sd[t] - v;
    if (t == 255) bsum[blockIdx.x] = sd[255];
}

// exclusive scan of the 391 block sums, in place
__global__ void k_scanB(int* __restrict__ bsum) {
    __shared__ int sd[512];
    int t = threadIdx.x;
    int v = (t < GBLK) ? bsum[t] : 0;
    sd[t] = v; __syncthreads();
#pragma unroll
    for (int o = 1; o < 512; o <<= 1) {
        int u = (t >= o) ? sd[t - o] : 0;
        __syncthreads();
        sd[t] += u;
        __syncthreads();
    }
    if (t < GBLK) bsum[t] = sd[t] - v;
}

__global__ void k_scanC(const int* __restrict__ loc, const int* __restrict__ bsum,
                        int* __restrict__ rowp, int* __restrict__ cursor) {
    int i = blockIdx.x * 256 + threadIdx.x;
    int r = loc[i] + bsum[blockIdx.x];
    rowp[i] = r;
    cursor[i] = r;
    if (i == 0) rowp[NN] = NE;   // overwritten below only if NN < NN2 (it is)
}

__global__ void k_fill(const int* __restrict__ ei, int* __restrict__ cursor,
                       int* __restrict__ csr) {
    int e = blockIdx.x * 256 + threadIdx.x;
    int s = ei[e], d = ei[NE + e];
    int pos = atomicAdd(&cursor[d], 1);
    csr[pos] = s;
}

// one wave per node: agg[n] = x[n] + sum_{j in CSR[n]} x[j], stored bf16
__global__ __launch_bounds__(256) void k_gather(const float* __restrict__ x,
                                                const int* __restrict__ rowp,
                                                const int* __restrict__ csr,
                                                ushort* __restrict__ agg) {
    int wave = threadIdx.x >> 6, lane = threadIdx.x & 63;
    int n = blockIdx.x * 4 + wave;
    if (n >= NN) return;
    int c0 = lane * 2;
    const float* xr = x + (size_t)n * DD + c0;
    float a0 = xr[0], a1 = xr[1];
    int rs = rowp[n], re = rowp[n + 1];
    int i = rs;
    for (; i + 4 <= re; i += 4) {
        int s0 = csr[i], s1 = csr[i + 1], s2 = csr[i + 2], s3 = csr[i + 3];
        float2 v0 = *(const float2*)(x + (size_t)s0 * DD + c0);
        float2 v1 = *(const float2*)(x + (size_t)s1 * DD + c0);
        float2 v2 = *(const float2*)(x + (size_t)s2 * DD + c0);
        float2 v3 = *(const float2*)(x + (size_t)s3 * DD + c0);
        a0 += v0.x + v1.x + v2.x + v3.x;
        a1 += v0.y + v1.y + v2.y + v3.y;
    }
    for (; i < re; ++i) {
        float2 v = *(const float2*)(x + (size_t)csr[i] * DD + c0);
        a0 += v.x; a1 += v.y;
    }
    uint pk = (uint)f2bf(a0) | ((uint)f2bf(a1) << 16);
    ((uint*)(agg + (size_t)n * DD))[lane] = pk;
}

// MODE 1: A = bf16 agg, no pre-transform, bias, bf16 out, emit colstats
// MODE 2: A = bf16 t1,  pre-transform relu(a*t+c), bias, bf16 out, emit colstats
// MODE 3: A = bf16 t2,  pre-transform relu(a*t+c), no bias, relu, fp32 out, no stats
template <int MODE>
__global__ __launch_bounds__(256) void k_gemm(const ushort* __restrict__ Ain,
                                              const float* __restrict__ W,
                                              const float* __restrict__ bias,
                                              const float* __restrict__ ac,
                                              void* __restrict__ Outv,
                                              float* __restrict__ stats) {
    __shared__ ushort lw[DD * 136];     // W[c][k] as bf16, row padded 128->136
    __shared__ float red[2][4][DD];

    int tid = threadIdx.x;
    // stage W (128x128 fp32 -> bf16) into LDS
#pragma unroll
    for (int it = 0; it < 8; ++it) {
        int idx = (it * 256 + tid) * 8;
        int r = idx >> 7, k = idx & 127;
        float4 u0 = *(const float4*)(W + idx);
        float4 u1 = *(const float4*)(W + idx + 4);
        uint4 pk;
        pk.x = (uint)f2bf(u0.x) | ((uint)f2bf(u0.y) << 16);
        pk.y = (uint)f2bf(u0.z) | ((uint)f2bf(u0.w) << 16);
        pk.z = (uint)f2bf(u1.x) | ((uint)f2bf(u1.y) << 16);
        pk.w = (uint)f2bf(u1.z) | ((uint)f2bf(u1.w) << 16);
        *(uint4*)&lw[r * 136 + k] = pk;
    }
    __syncthreads();

    int wave = tid >> 6, lane = tid & 63;
    int lm = lane & 15, quad = lane >> 4;
    int row0 = blockIdx.x * 64 + wave * 16;
    int arow = row0 + lm;
    int ar = (arow < NN) ? arow : 0;   // clamped rows produce garbage C rows we never store

    // A fragments: A[m=lane&15][k = kb*32 + quad*8 + j]
    bf16x8 afrag[4];
#pragma unroll
    for (int kb = 0; kb < 4; ++kb) {
        int k0 = kb * 32 + quad * 8;
        const ushort* ap = Ain + (size_t)ar * DD + k0;
        u4bf8 u; u.u = *(const uint4*)ap;
        if constexpr (MODE == 1) {
            afrag[kb] = u.v;
        } else {
            uint pk[4] = {u.u.x, u.u.y, u.u.z, u.u.w};
            bf16x8 af;
#pragma unroll
            for (int jj = 0; jj < 4; ++jj) {
                int k = k0 + jj * 2;
                float v0 = bf2f((ushort)(pk[jj] & 0xffffu));
                float v1 = bf2f((ushort)(pk[jj] >> 16));
                v0 = fmaxf(fmaf(v0, ac[k], ac[DD + k]), 0.f);
                v1 = fmaxf(fmaf(v1, ac[k + 1], ac[DD + k + 1]), 0.f);
                af[jj * 2]     = (short)f2bf(v0);
                af[jj * 2 + 1] = (short)f2bf(v1);
            }
            afrag[kb] = af;
        }
    }

    // accumulators; bias in C init (bias depends only on col)
    f32x4 acc[8];
#pragma unroll
    for (int nt = 0; nt < 8; ++nt) {
        float bv = (MODE == 3) ? 0.f : bias[nt * 16 + lm];
        acc[nt] = (f32x4){bv, bv, bv, bv};
    }

#pragma unroll
    for (int kb = 0; kb < 4; ++kb) {
#pragma unroll
        for (int nt = 0; nt < 8; ++nt) {
            bf16x8 bfrag = *(const bf16x8*)&lw[(nt * 16 + lm) * 136 + kb * 32 + quad * 8];
            acc[nt] = __builtin_amdgcn_mfma_f32_16x16x32_bf16(afrag[kb], bfrag, acc[nt], 0, 0, 0);
        }
    }

    // epilogue: store + column sum / sumsq; C/D: col=lane&15, row=quad*4+r
    ushort* Out16 = (ushort*)Outv;
    float* Out32 = (float*)Outv;
    float csum[8], csq[8];
#pragma unroll
    for (int nt = 0; nt < 8; ++nt) {
        int col = nt * 16 + lm;
        float s = 0.f, q = 0.f;
#pragma unroll
        for (int r = 0; r < 4; ++r) {
            int row = row0 + quad * 4 + r;
            float v = acc[nt][r];
            if (MODE == 3) v = fmaxf(v, 0.f);
            if (row < NN) {
                if constexpr (MODE == 3) Out32[(size_t)row * DD + col] = v;
                else Out16[(size_t)row * DD + col] = f2bf(v);
                s += v;
                q += v * v;
            }
        }
        csum[nt] = s; csq[nt] = q;
    }

    if constexpr (MODE != 3) {
#pragma unroll
        for (int nt = 0; nt < 8; ++nt) {
            float s = csum[nt], q = csq[nt];
            s += __shfl_down(s, 16, 64); q += __shfl_down(q, 16, 64);
            s += __shfl_down(s, 32, 64); q += __shfl_down(q, 32, 64);
            if (quad == 0) {
                red[0][wave][nt * 16 + lm] = s;
                red[1][wave][nt * 16 + lm] = q;
            }
        }
        __syncthreads();
        if (tid < DD) {
            float S = red[0][0][tid] + red[0][1][tid] + red[0][2][tid] + red[0][3][tid];
            float Q = red[1][0][tid] + red[1][1][tid] + red[1][2][tid] + red[1][3][tid];
            atomicAdd(&stats[tid], S);
            atomicAdd(&stats[DD + tid], Q);
        }
    }
}

// mean/var -> scale a, shift c for fused BN apply
__global__ void k_finalize(const float* __restrict__ stats, const float* __restrict__ g,
                           const float* __restrict__ be, float* __restrict__ ac) {
    int c = threadIdx.x;
    float inv = 1.f / (float)NN;
    float mean = stats[c] * inv;
    float var = stats[DD + c] * inv - mean * mean;
    float a = g[c] * rsqrtf(var + 1e-5f);
    ac[c] = a;
    ac[DD + c] = be[c] - mean * a;
}

extern "C" void kernel_launch(void* const* d_in, const int* in_sizes, int n_in,
                              void* d_out, int out_size, void* d_ws, size_t ws_size,
                              hipStream_t stream) {
    const float* x   = (const float*)d_in[0];
    const int* ei    = (const int*)d_in[1];
    const float* W1  = (const float*)d_in[2];
    const float* b1  = (const float*)d_in[3];
    const float* g1  = (const float*)d_in[4];
    const float* be1 = (const float*)d_in[5];
    const float* W2  = (const float*)d_in[6];
    const float* b2  = (const float*)d_in[7];
    const float* g2  = (const float*)d_in[8];
    const float* be2 = (const float*)d_in[9];
    const float* W3  = (const float*)d_in[10];

    // ws layout (all 16B-aligned):
    // stats f32[512] | ac f32[512] | deg i32[NN2] | loc i32[NN2] | bsum i32[512]
    // | rowp i32[NN2] | cursor i32[NN2] | csr i32[NE] | agg bf16[NN*DD] (reused as t2)
    float* stats = (float*)d_ws;
    float* ac    = stats + 512;
    int* deg     = (int*)(ac + 512);
    int* loc     = deg + NN2;
    int* bsum    = loc + NN2;
    int* rowp    = bsum + 512;
    int* cursor  = rowp + NN2;
    int* csr     = cursor + NN2;
    ushort* agg  = (ushort*)(csr + NE);
    ushort* t1   = (ushort*)d_out;      // bf16, dead before gemm3 writes fp32
    ushort* t2   = agg;                 // agg dead after gemm1
    float* outp  = (float*)d_out;

    int gblk = (NN + 63) / 64;
    k_zero<<<(NN2 + 512) / 256, 256, 0, stream>>>(deg, stats);
    k_hist<<<NE / 256, 256, 0, stream>>>(ei, deg);
    k_scanA<<<GBLK, 256, 0, stream>>>(deg, loc, bsum);
    k_scanB<<<1, 512, 0, stream>>>(bsum);
    k_scanC<<<GBLK, 256, 0, stream>>>(loc, bsum, rowp, cursor);
    k_fill<<<NE / 256, 256, 0, stream>>>(ei, cursor, csr);
    k_gather<<<(NN + 3) / 4, 256, 0, stream>>>(x, rowp, csr, agg);
    k_gemm<1><<<gblk, 256, 0, stream>>>(agg, W1, b1, nullptr, t1, stats);
    k_finalize<<<1, DD, 0, stream>>>(stats, g1, be1, ac);
    k_gemm<2><<<gblk, 256, 0, stream>>>(t1, W2, b2, ac, t2, stats + 256);
    k_finalize<<<1, DD, 0, stream>>>(stats + 256, g2, be2, ac + 256);
    k_gemm<3><<<gblk, 256, 0, stream>>>(t2, W3, nullptr, ac + 256, outp, nullptr);
}

// Round 4
// 507.307 us; speedup vs baseline: 3.0529x; 1.0574x over previous
//
#include <hip/hip_runtime.h>

#define NN 100000
#define NE 1600000
#define DD 128
#define NN2 100096   // 391*256, padded node count for scan
#define GBLK 391

typedef __attribute__((ext_vector_type(8))) short bf16x8;
typedef __attribute__((ext_vector_type(4))) float f32x4;

union u4bf8 { uint4 u; bf16x8 v; };

__device__ __forceinline__ ushort f2bf(float f) {
    union { float f; uint i; } v; v.f = f;
    uint i = v.i;
    return (ushort)((i + 0x7fffu + ((i >> 16) & 1u)) >> 16);
}
__device__ __forceinline__ float bf2f(ushort u) {
    union { uint i; float f; } v; v.i = ((uint)u) << 16; return v.f;
}

// xb (bf16 copy of x, in d_out) + zero degP (line-padded) + zero stats
__global__ void k_xb(const float* __restrict__ x, uint* __restrict__ xb,
                     int* __restrict__ degP, float* __restrict__ stats) {
    int gid = blockIdx.x * 256 + threadIdx.x;   // 1.6M threads
    if (gid < NN2 * 4) ((int4*)degP)[gid] = (int4){0, 0, 0, 0};
    else if (gid - NN2 * 4 < 512) stats[gid - NN2 * 4] = 0.f;
    float4 u0 = ((const float4*)x)[gid * 2];
    float4 u1 = ((const float4*)x)[gid * 2 + 1];
    uint4 pk;
    pk.x = (uint)f2bf(u0.x) | ((uint)f2bf(u0.y) << 16);
    pk.y = (uint)f2bf(u0.z) | ((uint)f2bf(u0.w) << 16);
    pk.z = (uint)f2bf(u1.x) | ((uint)f2bf(u1.y) << 16);
    pk.w = (uint)f2bf(u1.z) | ((uint)f2bf(u1.w) << 16);
    ((uint4*)xb)[gid] = pk;
}

// degree histogram into line-padded counters (1 counter per 64B line)
__global__ void k_hist(const int* __restrict__ ei, int* __restrict__ degP) {
    int e = blockIdx.x * 256 + threadIdx.x;
    atomicAdd(&degP[ei[NE + e] * 16], 1);
}

// per-block exclusive scan (256 elems) + block sums; reads padded histogram
__global__ void k_scanA(const int* __restrict__ degP, int* __restrict__ loc,
                        int* __restrict__ bsum) {
    __shared__ int sd[256];
    int t = threadIdx.x;
    int i = blockIdx.x * 256 + t;
    int v = degP[i * 16];
    sd[t] = v; __syncthreads();
#pragma unroll
    for (int o = 1; o < 256; o <<= 1) {
        int u = (t >= o) ? sd[t - o] : 0;
        __syncthreads();
        sd[t] += u;
        __syncthreads();
    }
    loc[i] = sd[t] - v;
    if (t == 255) bsum[blockIdx.x] = sd[255];
}

__global__ void k_scanB(int* __restrict__ bsum) {
    __shared__ int sd[512];
    int t = threadIdx.x;
    int v = (t < GBLK) ? bsum[t] : 0;
    sd[t] = v; __syncthreads();
#pragma unroll
    for (int o = 1; o < 512; o <<= 1) {
        int u = (t >= o) ? sd[t - o] : 0;
        __syncthreads();
        sd[t] += u;
        __syncthreads();
    }
    if (t < GBLK) bsum[t] = sd[t] - v;
}

__global__ void k_scanC(const int* __restrict__ loc, const int* __restrict__ bsum,
                        int* __restrict__ rowp, int* __restrict__ cursorP) {
    int i = blockIdx.x * 256 + threadIdx.x;
    int r = loc[i] + bsum[blockIdx.x];
    rowp[i] = r;
    cursorP[i * 16] = r;
}

__global__ void k_fill(const int* __restrict__ ei, int* __restrict__ cursorP,
                       int* __restrict__ csr) {
    int e = blockIdx.x * 256 + threadIdx.x;
    int s = ei[e], d = ei[NE + e];
    int pos = atomicAdd(&cursorP[d * 16], 1);
    csr[pos] = s;
}

// one wave per node: agg[n] = x[n] (fp32) + sum_{j in CSR[n]} xb[j] (bf16 rows)
__global__ __launch_bounds__(256) void k_gather(const float* __restrict__ x,
                                                const uint* __restrict__ xb,
                                                const int* __restrict__ rowp,
                                                const int* __restrict__ csr,
                                                ushort* __restrict__ agg) {
    int wave = threadIdx.x >> 6, lane = threadIdx.x & 63;
    int n = blockIdx.x * 4 + wave;
    if (n >= NN) return;
    float2 sv = ((const float2*)(x + (size_t)n * DD))[lane];
    float a0 = sv.x, a1 = sv.y;
    int rs = rowp[n], re = rowp[n + 1];
    int i = rs;
    for (; i + 4 <= re; i += 4) {
        int s0 = csr[i], s1 = csr[i + 1], s2 = csr[i + 2], s3 = csr[i + 3];
        uint v0 = xb[s0 * 64 + lane];
        uint v1 = xb[s1 * 64 + lane];
        uint v2 = xb[s2 * 64 + lane];
        uint v3 = xb[s3 * 64 + lane];
        a0 += bf2f((ushort)(v0 & 0xffffu)) + bf2f((ushort)(v1 & 0xffffu))
            + bf2f((ushort)(v2 & 0xffffu)) + bf2f((ushort)(v3 & 0xffffu));
        a1 += bf2f((ushort)(v0 >> 16)) + bf2f((ushort)(v1 >> 16))
            + bf2f((ushort)(v2 >> 16)) + bf2f((ushort)(v3 >> 16));
    }
    for (; i < re; ++i) {
        uint v = xb[csr[i] * 64 + lane];
        a0 += bf2f((ushort)(v & 0xffffu));
        a1 += bf2f((ushort)(v >> 16));
    }
    uint pk = (uint)f2bf(a0) | ((uint)f2bf(a1) << 16);
    ((uint*)(agg + (size_t)n * DD))[lane] = pk;
}

// MODE 1: A = bf16 agg, no pre-transform, bias, bf16 out, emit colstats
// MODE 2: A = bf16 t1,  pre-transform relu(a*t+c), bias, bf16 out, emit colstats
// MODE 3: A = bf16 t2,  pre-transform relu(a*t+c), no bias, relu, fp32 out, no stats
template <int MODE>
__global__ __launch_bounds__(256) void k_gemm(const ushort* __restrict__ Ain,
                                              const float* __restrict__ W,
                                              const float* __restrict__ bias,
                                              const float* __restrict__ ac,
                                              void* __restrict__ Outv,
                                              float* __restrict__ stats) {
    __shared__ ushort lw[DD * 136];     // W[c][k] as bf16, row padded 128->136
    __shared__ float red[2][4][DD];

    int tid = threadIdx.x;
#pragma unroll
    for (int it = 0; it < 8; ++it) {
        int idx = (it * 256 + tid) * 8;
        int r = idx >> 7, k = idx & 127;
        float4 u0 = *(const float4*)(W + idx);
        float4 u1 = *(const float4*)(W + idx + 4);
        uint4 pk;
        pk.x = (uint)f2bf(u0.x) | ((uint)f2bf(u0.y) << 16);
        pk.y = (uint)f2bf(u0.z) | ((uint)f2bf(u0.w) << 16);
        pk.z = (uint)f2bf(u1.x) | ((uint)f2bf(u1.y) << 16);
        pk.w = (uint)f2bf(u1.z) | ((uint)f2bf(u1.w) << 16);
        *(uint4*)&lw[r * 136 + k] = pk;
    }
    __syncthreads();

    int wave = tid >> 6, lane = tid & 63;
    int lm = lane & 15, quad = lane >> 4;
    int row0 = blockIdx.x * 64 + wave * 16;
    int arow = row0 + lm;
    int ar = (arow < NN) ? arow : 0;

    bf16x8 afrag[4];
#pragma unroll
    for (int kb = 0; kb < 4; ++kb) {
        int k0 = kb * 32 + quad * 8;
        const ushort* ap = Ain + (size_t)ar * DD + k0;
        u4bf8 u; u.u = *(const uint4*)ap;
        if constexpr (MODE == 1) {
            afrag[kb] = u.v;
        } else {
            uint pk[4] = {u.u.x, u.u.y, u.u.z, u.u.w};
            bf16x8 af;
#pragma unroll
            for (int jj = 0; jj < 4; ++jj) {
                int k = k0 + jj * 2;
                float v0 = bf2f((ushort)(pk[jj] & 0xffffu));
                float v1 = bf2f((ushort)(pk[jj] >> 16));
                v0 = fmaxf(fmaf(v0, ac[k], ac[DD + k]), 0.f);
                v1 = fmaxf(fmaf(v1, ac[k + 1], ac[DD + k + 1]), 0.f);
                af[jj * 2]     = (short)f2bf(v0);
                af[jj * 2 + 1] = (short)f2bf(v1);
            }
            afrag[kb] = af;
        }
    }

    f32x4 acc[8];
#pragma unroll
    for (int nt = 0; nt < 8; ++nt) {
        float bv = (MODE == 3) ? 0.f : bias[nt * 16 + lm];
        acc[nt] = (f32x4){bv, bv, bv, bv};
    }

#pragma unroll
    for (int kb = 0; kb < 4; ++kb) {
#pragma unroll
        for (int nt = 0; nt < 8; ++nt) {
            bf16x8 bfrag = *(const bf16x8*)&lw[(nt * 16 + lm) * 136 + kb * 32 + quad * 8];
            acc[nt] = __builtin_amdgcn_mfma_f32_16x16x32_bf16(afrag[kb], bfrag, acc[nt], 0, 0, 0);
        }
    }

    ushort* Out16 = (ushort*)Outv;
    float* Out32 = (float*)Outv;
    float csum[8], csq[8];
#pragma unroll
    for (int nt = 0; nt < 8; ++nt) {
        int col = nt * 16 + lm;
        float s = 0.f, q = 0.f;
#pragma unroll
        for (int r = 0; r < 4; ++r) {
            int row = row0 + quad * 4 + r;
            float v = acc[nt][r];
            if (MODE == 3) v = fmaxf(v, 0.f);
            if (row < NN) {
                if constexpr (MODE == 3) Out32[(size_t)row * DD + col] = v;
                else Out16[(size_t)row * DD + col] = f2bf(v);
                s += v;
                q += v * v;
            }
        }
        csum[nt] = s; csq[nt] = q;
    }

    if constexpr (MODE != 3) {
#pragma unroll
        for (int nt = 0; nt < 8; ++nt) {
            float s = csum[nt], q = csq[nt];
            s += __shfl_down(s, 16, 64); q += __shfl_down(q, 16, 64);
            s += __shfl_down(s, 32, 64); q += __shfl_down(q, 32, 64);
            if (quad == 0) {
                red[0][wave][nt * 16 + lm] = s;
                red[1][wave][nt * 16 + lm] = q;
            }
        }
        __syncthreads();
        if (tid < DD) {
            float S = red[0][0][tid] + red[0][1][tid] + red[0][2][tid] + red[0][3][tid];
            float Q = red[1][0][tid] + red[1][1][tid] + red[1][2][tid] + red[1][3][tid];
            atomicAdd(&stats[tid], S);
            atomicAdd(&stats[DD + tid], Q);
        }
    }
}

__global__ void k_finalize(const float* __restrict__ stats, const float* __restrict__ g,
                           const float* __restrict__ be, float* __restrict__ ac) {
    int c = threadIdx.x;
    float inv = 1.f / (float)NN;
    float mean = stats[c] * inv;
    float var = stats[DD + c] * inv - mean * mean;
    float a = g[c] * rsqrtf(var + 1e-5f);
    ac[c] = a;
    ac[DD + c] = be[c] - mean * a;
}

extern "C" void kernel_launch(void* const* d_in, const int* in_sizes, int n_in,
                              void* d_out, int out_size, void* d_ws, size_t ws_size,
                              hipStream_t stream) {
    const float* x   = (const float*)d_in[0];
    const int* ei    = (const int*)d_in[1];
    const float* W1  = (const float*)d_in[2];
    const float* b1  = (const float*)d_in[3];
    const float* g1  = (const float*)d_in[4];
    const float* be1 = (const float*)d_in[5];
    const float* W2  = (const float*)d_in[6];
    const float* b2  = (const float*)d_in[7];
    const float* g2  = (const float*)d_in[8];
    const float* be2 = (const float*)d_in[9];
    const float* W3  = (const float*)d_in[10];

    // ws: stats f32[512] | ac f32[512] | degP i32[NN2*16] | loc i32[NN2]
    //   | bsum i32[512] | rowp i32[NN2] | cursorP i32[NN2*16] | csr i32[NE]
    //   | agg bf16[NN*DD] (reused as t2)          total ~45.6 MB
    float* stats = (float*)d_ws;
    float* ac    = stats + 512;
    int* degP    = (int*)(ac + 512);
    int* loc     = degP + (size_t)NN2 * 16;
    int* bsum    = loc + NN2;
    int* rowp    = bsum + 512;
    int* cursorP = rowp + NN2;
    int* csr     = cursorP + (size_t)NN2 * 16;
    ushort* agg  = (ushort*)(csr + NE);
    // d_out (51.2 MB fp32): first half = xb (bf16 x copy), second half = t1
    uint* xb     = (uint*)d_out;
    ushort* t1   = (ushort*)d_out + (size_t)NN * DD;
    ushort* t2   = agg;                 // agg dead after gemm1
    float* outp  = (float*)d_out;

    int gblk = (NN + 63) / 64;
    k_xb<<<NN * DD / 8 / 256, 256, 0, stream>>>(x, xb, degP, stats);
    k_hist<<<NE / 256, 256, 0, stream>>>(ei, degP);
    k_scanA<<<GBLK, 256, 0, stream>>>(degP, loc, bsum);
    k_scanB<<<1, 512, 0, stream>>>(bsum);
    k_scanC<<<GBLK, 256, 0, stream>>>(loc, bsum, rowp, cursorP);
    k_fill<<<NE / 256, 256, 0, stream>>>(ei, cursorP, csr);
    k_gather<<<(NN + 3) / 4, 256, 0, stream>>>(x, xb, rowp, csr, agg);
    k_gemm<1><<<gblk, 256, 0, stream>>>(agg, W1, b1, nullptr, t1, stats);
    k_finalize<<<1, DD, 0, stream>>>(stats, g1, be1, ac);
    k_gemm<2><<<gblk, 256, 0, stream>>>(t1, W2, b2, ac, t2, stats + 256);
    k_finalize<<<1, DD, 0, stream>>>(stats + 256, g2, be2, ac + 256);
    k_gemm<3><<<gblk, 256, 0, stream>>>(t2, W3, nullptr, ac + 256, outp, nullptr);
}